// Round 8
// baseline (350.674 us; speedup 1.0000x reference)
//
#include <hip/hip_runtime.h>
#include <hip/hip_fp16.h>

#define NN 50000
#define NE 800000
#define D 64
#define EPS 1e-5f
#define PAD 16   // ints per counter slot -> one 64B line each
#define NT 3125  // NN/16 row-tiles for MFMA GEMMs

typedef unsigned short ushort_t;
typedef unsigned int uint_t;
typedef __attribute__((ext_vector_type(8))) short bf16x8;
typedef __attribute__((ext_vector_type(4))) float f32x4;

__device__ __forceinline__ float wave_sum64(float v) {
#pragma unroll
  for (int m = 1; m <= 32; m <<= 1) v += __shfl_xor(v, m, 64);
  return v;
}
__device__ __forceinline__ float group_sum16(float v) {
#pragma unroll
  for (int m = 1; m <= 8; m <<= 1) v += __shfl_xor(v, m, 64);
  return v;
}
__device__ __forceinline__ float silu_f(float v) { return v / (1.f + __expf(-v)); }
__device__ __forceinline__ float lrelu_f(float v) { return v >= 0.f ? v : 0.2f * v; }
__device__ __forceinline__ ushort_t f2b(float x) {
  unsigned u = __float_as_uint(x);
  return (ushort_t)((u + 0x7FFFu + ((u >> 16) & 1u)) >> 16);
}
__device__ __forceinline__ float b2f(ushort_t u) {
  return __uint_as_float(((unsigned)u) << 16);
}
__device__ __forceinline__ float blo(uint_t v) {
  return __uint_as_float(v << 16);
}
__device__ __forceinline__ float bhi(uint_t v) {
  return __uint_as_float(v & 0xFFFF0000u);
}
__device__ __forceinline__ ushort_t f2h(float x) {
  return __half_as_ushort(__float2half_rn(x));
}
__device__ __forceinline__ float h2f(unsigned u) {
  return __half2float(__ushort_as_half((ushort_t)(u & 0xFFFFu)));
}
__device__ __forceinline__ float sel4(float a, float b, float c, float d, int h) {
  float ab = (h & 1) ? b : a;
  float cd = (h & 1) ? d : c;
  return (h & 2) ? cd : ab;
}
__device__ __forceinline__ bf16x8 pack8(float4 a, float4 b) {
  bf16x8 r;
  r[0] = (short)f2b(a.x); r[1] = (short)f2b(a.y);
  r[2] = (short)f2b(a.z); r[3] = (short)f2b(a.w);
  r[4] = (short)f2b(b.x); r[5] = (short)f2b(b.y);
  r[6] = (short)f2b(b.z); r[7] = (short)f2b(b.w);
  return r;
}

// ---------- graph preprocessing ----------
__global__ void k_histrank(const int* __restrict__ ei, int* __restrict__ cnt_p,
                           int* __restrict__ rank) {
  int e = blockIdx.x * blockDim.x + threadIdx.x;
  if (e >= NE) return;
  int dst = ei[NE + e];
  rank[e] = atomicAdd(&cnt_p[(size_t)dst * PAD], 1);
}

__global__ void k_scanA(const int* __restrict__ cnt_p, int* __restrict__ rs,
                        int* __restrict__ bsum) {
  __shared__ int sm[256];
  int j = threadIdx.x, i = blockIdx.x * 256 + j;
  int v = (i < NN) ? cnt_p[(size_t)i * PAD] : 0;
  sm[j] = v;
  __syncthreads();
  for (int off = 1; off < 256; off <<= 1) {
    int t = (j >= off) ? sm[j - off] : 0;
    __syncthreads();
    sm[j] += t;
    __syncthreads();
  }
  if (i < NN) rs[i] = sm[j] - v;
  if (j == 255) bsum[blockIdx.x] = sm[255];
}

__global__ void k_scanB(const int* __restrict__ bsum, int* __restrict__ boff) {
  __shared__ int sm[256];
  int j = threadIdx.x;
  const int nb = (NN + 255) / 256;
  int v = (j < nb) ? bsum[j] : 0;
  sm[j] = v;
  __syncthreads();
  for (int off = 1; off < 256; off <<= 1) {
    int t = (j >= off) ? sm[j - off] : 0;
    __syncthreads();
    sm[j] += t;
    __syncthreads();
  }
  if (j < nb) boff[j] = sm[j] - v;
}

__global__ void k_scanC(int* __restrict__ rs, const int* __restrict__ boff) {
  int i = blockIdx.x * blockDim.x + threadIdx.x;
  if (i < NN) rs[i] = rs[i] + boff[i >> 8];
  if (i == 0) rs[NN] = NE;
}

__global__ void k_place(const int* __restrict__ ei, const float* __restrict__ ew,
                        const float* __restrict__ ea, const int* __restrict__ rank,
                        const int* __restrict__ rs,
                        uint2* __restrict__ rec, float* __restrict__ scal) {
  int e = blockIdx.x * blockDim.x + threadIdx.x;
  float a = 0.f;
  if (e < NE) {
    int src = ei[e];
    int dst = ei[NE + e];
    float w = ew[e];
    a = ea[e];
    int slot = rs[dst] + rank[e];
    uint2 r;
    r.x = (uint_t)(src & 0xFFFF) | ((uint_t)f2h(w) << 16);
    r.y = (uint_t)(src & 0xFFFF) | ((uint_t)f2h(a) << 16);
    rec[slot] = r;
  }
  float s = wave_sum64(a);
  if ((threadIdx.x & 63) == 0) {
    int slot = (blockIdx.x * 4 + (threadIdx.x >> 6)) & 63;
    atomicAdd(&scal[(size_t)slot * 16], s);
  }
}

__global__ void k_deg(const uint_t* __restrict__ rec, const int* __restrict__ rs,
                      float* __restrict__ dinv, float* __restrict__ scal) {
  int i = blockIdx.x * blockDim.x + threadIdx.x;
  if (i < NN) {
    float s = 1.f;
    int k1 = rs[i + 1];
    for (int k = rs[i]; k < k1; ++k) s += h2f(rec[2 * k] >> 16);
    dinv[i] = rsqrtf(s);
  }
  if (i == 0) {
    float t = 0.f;
    for (int j = 0; j < 64; ++j) t += scal[(size_t)j * 16];
    scal[1] = t / (float)NE;
  }
}

// ---------- MFMA dense ops (unchanged from R7) ----------
__global__ void __launch_bounds__(256) k_dual_gemm(
    const float* __restrict__ x, const float* __restrict__ W1,
    const float* __restrict__ W2, const float* __restrict__ b2,
    ushort_t* __restrict__ out1, float* __restrict__ out2) {
  __shared__ ushort_t wf[2 * 2 * 4 * 512];
  for (int e = threadIdx.x; e < 8192; e += 256) {
    int f = e >> 9, r = e & 511;
    int lane = r >> 3, j = r & 7;
    int m = f >> 3, s = (f >> 2) & 1, t = f & 3;
    int k = s * 32 + (lane >> 4) * 8 + j;
    int n = t * 16 + (lane & 15);
    const float* Wm = m ? W2 : W1;
    wf[e] = f2b(Wm[k * D + n]);
  }
  __syncthreads();
  int tile = blockIdx.x * 4 + (threadIdx.x >> 6);
  if (tile >= NT) return;
  int l = threadIdx.x & 63;
  int q = l >> 4, cn = l & 15;
  const float* xr = x + ((size_t)tile * 16 + cn) * D + q * 8;
  float4 xa = *(const float4*)xr;
  float4 xb = *(const float4*)(xr + 4);
  float4 xc = *(const float4*)(xr + 32);
  float4 xd = *(const float4*)(xr + 36);
  bf16x8 a0 = pack8(xa, xb), a1 = pack8(xc, xd);
  f32x4 acc1[4], acc2[4];
#pragma unroll
  for (int t = 0; t < 4; ++t) {
    bf16x8 b10 = *(const bf16x8*)&wf[(0 * 8 + 0 * 4 + t) * 512 + l * 8];
    bf16x8 b11 = *(const bf16x8*)&wf[(0 * 8 + 1 * 4 + t) * 512 + l * 8];
    bf16x8 b20 = *(const bf16x8*)&wf[(1 * 8 + 0 * 4 + t) * 512 + l * 8];
    bf16x8 b21 = *(const bf16x8*)&wf[(1 * 8 + 1 * 4 + t) * 512 + l * 8];
    f32x4 z = {0.f, 0.f, 0.f, 0.f};
    acc1[t] = __builtin_amdgcn_mfma_f32_16x16x32_bf16(a0, b10, z, 0, 0, 0);
    acc1[t] = __builtin_amdgcn_mfma_f32_16x16x32_bf16(a1, b11, acc1[t], 0, 0, 0);
    acc2[t] = __builtin_amdgcn_mfma_f32_16x16x32_bf16(a0, b20, z, 0, 0, 0);
    acc2[t] = __builtin_amdgcn_mfma_f32_16x16x32_bf16(a1, b21, acc2[t], 0, 0, 0);
  }
#pragma unroll
  for (int t = 0; t < 4; ++t) {
    float bb = b2[t * 16 + cn];
#pragma unroll
    for (int r = 0; r < 4; ++r) {
      size_t row = (size_t)tile * 16 + q * 4 + r;
      out1[row * D + t * 16 + cn] = f2b(acc1[t][r]);
      out2[row * D + t * 16 + cn] = acc2[t][r] + bb;
    }
  }
}

__global__ void __launch_bounds__(256) k_gat_node(
    const float* __restrict__ x2, const float* __restrict__ Wg,
    const float* __restrict__ att_src, const float* __restrict__ att_dst,
    const float* __restrict__ We, const float* __restrict__ a_e,
    ushort_t* __restrict__ xl, float* __restrict__ a_s, float* __restrict__ a_d,
    float* __restrict__ wea) {
  __shared__ ushort_t wf[2 * 4 * 512];
  for (int e = threadIdx.x; e < 4096; e += 256) {
    int f = e >> 9, r = e & 511;
    int lane = r >> 3, j = r & 7;
    int s = (f >> 2) & 1, t = f & 3;
    int k = s * 32 + (lane >> 4) * 8 + j;
    int n = t * 16 + (lane & 15);
    wf[e] = f2b(Wg[k * D + n]);
  }
  __syncthreads();
  if (blockIdx.x == 0 && threadIdx.x < 64) {
    int c = threadIdx.x;
    float v = group_sum16(We[c] * a_e[c]);
    if ((c & 15) == 0) wea[c >> 4] = v;
  }
  int tile = blockIdx.x * 4 + (threadIdx.x >> 6);
  if (tile >= NT) return;
  int l = threadIdx.x & 63;
  int q = l >> 4, cn = l & 15;
  const float* xr = x2 + ((size_t)tile * 16 + cn) * D + q * 8;
  float4 xa = *(const float4*)xr;
  float4 xb = *(const float4*)(xr + 4);
  float4 xc = *(const float4*)(xr + 32);
  float4 xd = *(const float4*)(xr + 36);
  bf16x8 a0 = pack8(xa, xb), a1 = pack8(xc, xd);
  f32x4 acc[4];
#pragma unroll
  for (int t = 0; t < 4; ++t) {
    bf16x8 b0 = *(const bf16x8*)&wf[(0 * 4 + t) * 512 + l * 8];
    bf16x8 b1 = *(const bf16x8*)&wf[(1 * 4 + t) * 512 + l * 8];
    f32x4 z = {0.f, 0.f, 0.f, 0.f};
    acc[t] = __builtin_amdgcn_mfma_f32_16x16x32_bf16(a0, b0, z, 0, 0, 0);
    acc[t] = __builtin_amdgcn_mfma_f32_16x16x32_bf16(a1, b1, acc[t], 0, 0, 0);
  }
#pragma unroll
  for (int t = 0; t < 4; ++t) {
    float av = att_src[t * 16 + cn];
    float dv = att_dst[t * 16 + cn];
#pragma unroll
    for (int r = 0; r < 4; ++r) {
      size_t row = (size_t)tile * 16 + q * 4 + r;
      xl[row * D + t * 16 + cn] = f2b(acc[t][r]);
      float vs = group_sum16(acc[t][r] * av);
      float vd = group_sum16(acc[t][r] * dv);
      if (cn == 0) {
        a_s[row * 4 + t] = vs;
        a_d[row * 4 + t] = vd;
      }
    }
  }
}

// ---------- aggregation: packed 2-col lanes, half-waves process alternate
// edges -> one vmem instruction gathers TWO edges' rows. ----------

// GCN aggregate + bias + silu + residual + LayerNorm. One wave per node.
__global__ void __launch_bounds__(256) k_gcn_agg(
    const ushort_t* __restrict__ h16, const float* __restrict__ res,
    const float* __restrict__ dinv, const int* __restrict__ rs,
    const uint_t* __restrict__ rec,
    const float* __restrict__ gb, const float* __restrict__ lg, const float* __restrict__ lb,
    float* __restrict__ x2, int n) {
  __shared__ int   ss[4][64];
  __shared__ float swt[4][64];
  int w = threadIdx.x >> 6;
  int i = (blockIdx.x * blockDim.x + threadIdx.x) >> 6;
  int l = threadIdx.x & 63;
  if (i >= n) return;
  int half = l >> 5, cp = l & 31, c0 = cp * 2;
  float di = dinv[i];
  float acc0 = 0.f, acc1 = 0.f;
  if (half == 0) {
    uint_t hv = *(const uint_t*)&h16[(size_t)i * D + c0];
    float sw = di * di;
    acc0 = sw * blo(hv);
    acc1 = sw * bhi(hv);
  }
  int k0 = rs[i], k1 = rs[i + 1];
  for (int base = k0; base < k1; base += 64) {
    int cnt = min(64, k1 - base);
    int src = 0; float wn = 0.f;
    if (l < cnt) {
      uint_t r = rec[2 * (size_t)(base + l)];
      src = (int)(r & 0xFFFFu);
      wn = dinv[src] * h2f(r >> 16) * di;
    }
    ss[w][l] = src;
    swt[w][l] = wn;
    int nit = (cnt + 1) >> 1;  // ceil(cnt/2); padded slots carry w=0
    int j2 = 0;
    for (; j2 + 4 <= nit; j2 += 4) {
      int ja = 2 * j2 + half;
      int s0 = ss[w][ja],     s1 = ss[w][ja + 2];
      int s2 = ss[w][ja + 4], s3 = ss[w][ja + 6];
      float w0 = swt[w][ja],     w1 = swt[w][ja + 2];
      float w2 = swt[w][ja + 4], w3 = swt[w][ja + 6];
      uint_t v0 = *(const uint_t*)&h16[(size_t)s0 * D + c0];
      uint_t v1 = *(const uint_t*)&h16[(size_t)s1 * D + c0];
      uint_t v2 = *(const uint_t*)&h16[(size_t)s2 * D + c0];
      uint_t v3 = *(const uint_t*)&h16[(size_t)s3 * D + c0];
      acc0 = fmaf(w0, blo(v0), acc0); acc1 = fmaf(w0, bhi(v0), acc1);
      acc0 = fmaf(w1, blo(v1), acc0); acc1 = fmaf(w1, bhi(v1), acc1);
      acc0 = fmaf(w2, blo(v2), acc0); acc1 = fmaf(w2, bhi(v2), acc1);
      acc0 = fmaf(w3, blo(v3), acc0); acc1 = fmaf(w3, bhi(v3), acc1);
    }
    for (; j2 < nit; ++j2) {
      int j = 2 * j2 + half;
      int s = ss[w][j];
      float wt = swt[w][j];
      uint_t v = *(const uint_t*)&h16[(size_t)s * D + c0];
      acc0 = fmaf(wt, blo(v), acc0);
      acc1 = fmaf(wt, bhi(v), acc1);
    }
  }
  acc0 += __shfl_xor(acc0, 32, 64);
  acc1 += __shfl_xor(acc1, 32, 64);
  float2 gbv = *(const float2*)(gb + c0);
  float2 rv  = *(const float2*)(res + (size_t)i * D + c0);
  float x10 = silu_f(acc0 + gbv.x) + rv.x;
  float x11 = silu_f(acc1 + gbv.y) + rv.y;
  float mu = wave_sum64(x10 + x11) * (1.f / 128.f);
  float d0 = x10 - mu, d1 = x11 - mu;
  float var = wave_sum64(d0 * d0 + d1 * d1) * (1.f / 128.f);
  float rstd = rsqrtf(var + EPS);
  if (half == 0) {
    float2 lgv = *(const float2*)(lg + c0);
    float2 lbv = *(const float2*)(lb + c0);
    float2 o;
    o.x = d0 * rstd * lgv.x + lbv.x;
    o.y = d1 * rstd * lgv.y + lbv.y;
    *(float2*)(x2 + (size_t)i * D + c0) = o;
  }
}

// GAT aggregate (no-max softmax), packed 2-col lanes.
__global__ void __launch_bounds__(256) k_gat_agg(
    const ushort_t* __restrict__ xl16, const float* __restrict__ x2,
    const float* __restrict__ a_s, const float* __restrict__ a_d,
    const int* __restrict__ rs, const uint_t* __restrict__ rec,
    const float* __restrict__ wea, const float* __restrict__ scal,
    const float* __restrict__ bg, float* __restrict__ xout, int n) {
  __shared__ int   ss[4][64];
  __shared__ float el[4][4][68];
  int w = threadIdx.x >> 6;
  int i = (blockIdx.x * blockDim.x + threadIdx.x) >> 6;
  int l = threadIdx.x & 63;
  if (i >= n) return;
  int half = l >> 5, cp = l & 31, c0 = cp * 2;
  int hh = cp >> 3;  // head of this col pair
  float4 ad4 = *(const float4*)(a_d + (size_t)i * 4);
  float4 wv4 = *(const float4*)wea;
  float mean_attr = scal[1];
  float ad_h = sel4(ad4.x, ad4.y, ad4.z, ad4.w, hh);
  float we_h = sel4(wv4.x, wv4.y, wv4.z, wv4.w, hh);
  float as_i = a_s[(size_t)i * 4 + hh];
  float s_acc = 0.f, acc0 = 0.f, acc1 = 0.f;
  if (half == 0) {
    float e_self = __expf(lrelu_f(as_i + ad_h + mean_attr * we_h));
    uint_t xv = *(const uint_t*)&xl16[(size_t)i * D + c0];
    s_acc = e_self;
    acc0 = e_self * blo(xv);
    acc1 = e_self * bhi(xv);
  }
  int k0 = rs[i], k1 = rs[i + 1];
  for (int base = k0; base < k1; base += 64) {
    int cnt = min(64, k1 - base);
    int src = 0;
    float e0v = 0.f, e1v = 0.f, e2v = 0.f, e3v = 0.f;
    if (l < cnt) {
      uint_t r = rec[2 * (size_t)(base + l) + 1];
      src = (int)(r & 0xFFFFu);
      float ea = h2f(r >> 16);
      float4 as4 = *(const float4*)(a_s + (size_t)src * 4);
      e0v = __expf(lrelu_f(as4.x + fmaf(ea, wv4.x, ad4.x)));
      e1v = __expf(lrelu_f(as4.y + fmaf(ea, wv4.y, ad4.y)));
      e2v = __expf(lrelu_f(as4.z + fmaf(ea, wv4.z, ad4.z)));
      e3v = __expf(lrelu_f(as4.w + fmaf(ea, wv4.w, ad4.w)));
    }
    ss[w][l] = src;
    el[w][0][l] = e0v;
    el[w][1][l] = e1v;
    el[w][2][l] = e2v;
    el[w][3][l] = e3v;
    int nit = (cnt + 1) >> 1;  // padded slots carry exp=0
    int j2 = 0;
    for (; j2 + 4 <= nit; j2 += 4) {
      int ja = 2 * j2 + half;
      int s0 = ss[w][ja],     s1 = ss[w][ja + 2];
      int s2 = ss[w][ja + 4], s3 = ss[w][ja + 6];
      float e0 = el[w][hh][ja],     e1 = el[w][hh][ja + 2];
      float e2 = el[w][hh][ja + 4], e3 = el[w][hh][ja + 6];
      uint_t v0 = *(const uint_t*)&xl16[(size_t)s0 * D + c0];
      uint_t v1 = *(const uint_t*)&xl16[(size_t)s1 * D + c0];
      uint_t v2 = *(const uint_t*)&xl16[(size_t)s2 * D + c0];
      uint_t v3 = *(const uint_t*)&xl16[(size_t)s3 * D + c0];
      acc0 = fmaf(e0, blo(v0), acc0); acc1 = fmaf(e0, bhi(v0), acc1);
      acc0 = fmaf(e1, blo(v1), acc0); acc1 = fmaf(e1, bhi(v1), acc1);
      acc0 = fmaf(e2, blo(v2), acc0); acc1 = fmaf(e2, bhi(v2), acc1);
      acc0 = fmaf(e3, blo(v3), acc0); acc1 = fmaf(e3, bhi(v3), acc1);
      s_acc += (e0 + e1) + (e2 + e3);
    }
    for (; j2 < nit; ++j2) {
      int j = 2 * j2 + half;
      int s = ss[w][j];
      float e = el[w][hh][j];
      uint_t v = *(const uint_t*)&xl16[(size_t)s * D + c0];
      acc0 = fmaf(e, blo(v), acc0);
      acc1 = fmaf(e, bhi(v), acc1);
      s_acc += e;
    }
  }
  acc0 += __shfl_xor(acc0, 32, 64);
  acc1 += __shfl_xor(acc1, 32, 64);
  s_acc += __shfl_xor(s_acc, 32, 64);
  if (half == 0) {
    float rinv = 1.f / (s_acc + 1e-16f);
    float2 bgv = *(const float2*)(bg + c0);
    float2 xv  = *(const float2*)(x2 + (size_t)i * D + c0);
    float2 o;
    o.x = silu_f(acc0 * rinv + bgv.x) + xv.x;
    o.y = silu_f(acc1 * rinv + bgv.y) + xv.y;
    *(float2*)(xout + (size_t)i * D + c0) = o;
  }
}

// ---------- launch ----------

extern "C" void kernel_launch(void* const* d_in, const int* in_sizes, int n_in,
                              void* d_out, int out_size, void* d_ws, size_t ws_size,
                              hipStream_t stream) {
  (void)in_sizes; (void)n_in; (void)out_size; (void)ws_size;
  const float* x  = (const float*)d_in[0];
  const int*   ei = (const int*)d_in[1];
  const float* ew = (const float*)d_in[2];
  const float* ea = (const float*)d_in[3];
  const float* P[2][12];
  for (int l = 0; l < 2; ++l)
    for (int j = 0; j < 12; ++j) P[l][j] = (const float*)d_in[4 + l * 12 + j];

  float* W = (float*)d_ws;
  const size_t o_rs    = 0;                          // NN+16 ints
  const size_t o_dinv  = o_rs + NN + 16;             // NN
  const size_t o_bsum  = o_dinv + NN;                // 256
  const size_t o_boff  = o_bsum + 256;               // 256
  const size_t o_wea   = o_boff + 256;               // 16
  const size_t o_scal  = o_wea + 16;                 // 1024 (contiguous w/ cnt_p)
  const size_t o_cnt   = o_scal + 1024;              // NN*PAD ints
  const size_t o_rec   = o_cnt + (size_t)NN * PAD;   // NE uint2
  const size_t o_h16   = o_rec + (size_t)NE * 2;     // NN*D ushort
  const size_t o_xl16  = o_h16 + (size_t)NN * D / 2;
  const size_t o_res   = o_xl16 + (size_t)NN * D / 2;
  const size_t o_x2    = o_res + (size_t)NN * D;
  const size_t o_xmid  = o_x2 + (size_t)NN * D;      // aliases rank in prep
  const size_t o_as    = o_xmid + (size_t)NN * D;    // NN*4
  const size_t o_ad    = o_as + (size_t)NN * 4;      // NN*4

  int*      rs    = (int*)(W + o_rs);
  float*    dinv  = W + o_dinv;
  int*      bsum  = (int*)(W + o_bsum);
  int*      boff  = (int*)(W + o_boff);
  float*    wea   = W + o_wea;
  float*    scal  = W + o_scal;
  int*      cnt_p = (int*)(W + o_cnt);
  uint2*    rec   = (uint2*)(W + o_rec);
  ushort_t* h16   = (ushort_t*)(W + o_h16);
  ushort_t* xl16  = (ushort_t*)(W + o_xl16);
  float*    resb  = W + o_res;
  float*    x2b   = W + o_x2;
  float*    xmid  = W + o_xmid;
  float*    asb   = W + o_as;
  float*    adb   = W + o_ad;
  int*      rank  = (int*)xmid;  // prep alias

  const int B = 256;
  const int gN  = (NN + B - 1) / B;
  const int gE  = (NE + B - 1) / B;
  const int gNW = (NN * D + B - 1) / B;   // wave per node (agg kernels)
  const int gMF = (NT + 3) / 4;           // 4 tiles (waves) per block

  hipMemsetAsync(W + o_scal, 0, (1024 + (size_t)NN * PAD) * sizeof(float), stream);
  k_histrank<<<gE, B, 0, stream>>>(ei, cnt_p, rank);
  k_scanA<<<gN, 256, 0, stream>>>(cnt_p, rs, bsum);
  k_scanB<<<1, 256, 0, stream>>>(bsum, boff);
  k_scanC<<<gN, B, 0, stream>>>(rs, boff);
  k_place<<<gE, B, 0, stream>>>(ei, ew, ea, rank, rs, rec, scal);
  k_deg<<<gN, B, 0, stream>>>((const uint_t*)rec, rs, dinv, scal);

  const float* xin = x;
  for (int l = 0; l < 2; ++l) {
    float* xout = (l == 0) ? xmid : (float*)d_out;
    k_dual_gemm<<<gMF, B, 0, stream>>>(xin, P[l][0], P[l][2], P[l][3], h16, resb);
    k_gcn_agg<<<gNW, B, 0, stream>>>(h16, resb, dinv, rs, (const uint_t*)rec,
                                     P[l][1], P[l][4], P[l][5], x2b, NN);
    k_gat_node<<<gMF, B, 0, stream>>>(x2b, P[l][6], P[l][8], P[l][9],
                                      P[l][11], P[l][10], xl16, asb, adb, wea);
    k_gat_agg<<<gNW, B, 0, stream>>>(xl16, x2b, asb, adb, rs, (const uint_t*)rec,
                                     wea, scal, P[l][7], xout, NN);
    xin = xout;
  }
}

// Round 9
// 336.303 us; speedup vs baseline: 1.0427x; 1.0427x over previous
//
#include <hip/hip_runtime.h>
#include <hip/hip_fp16.h>

#define NN 50000
#define NE 800000
#define D 64
#define EPS 1e-5f
#define PAD 16   // ints per counter slot -> one 64B line each
#define NT 3125  // NN/16 row-tiles for MFMA GEMMs

typedef unsigned short ushort_t;
typedef unsigned int uint_t;
typedef __attribute__((ext_vector_type(8))) short bf16x8;
typedef __attribute__((ext_vector_type(4))) float f32x4;

__device__ __forceinline__ float wave_sum64(float v) {
#pragma unroll
  for (int m = 1; m <= 32; m <<= 1) v += __shfl_xor(v, m, 64);
  return v;
}
__device__ __forceinline__ float group_sum16(float v) {
#pragma unroll
  for (int m = 1; m <= 8; m <<= 1) v += __shfl_xor(v, m, 64);
  return v;
}
__device__ __forceinline__ float silu_f(float v) { return v / (1.f + __expf(-v)); }
__device__ __forceinline__ float lrelu_f(float v) { return v >= 0.f ? v : 0.2f * v; }
__device__ __forceinline__ ushort_t f2b(float x) {
  unsigned u = __float_as_uint(x);
  return (ushort_t)((u + 0x7FFFu + ((u >> 16) & 1u)) >> 16);
}
__device__ __forceinline__ float b2f(ushort_t u) {
  return __uint_as_float(((unsigned)u) << 16);
}
__device__ __forceinline__ ushort_t f2h(float x) {
  return __half_as_ushort(__float2half_rn(x));
}
__device__ __forceinline__ float h2f(unsigned u) {
  return __half2float(__ushort_as_half((ushort_t)(u & 0xFFFFu)));
}
__device__ __forceinline__ float sel4(float a, float b, float c, float d, int h) {
  float ab = (h & 1) ? b : a;
  float cd = (h & 1) ? d : c;
  return (h & 2) ? cd : ab;
}
__device__ __forceinline__ bf16x8 pack8(float4 a, float4 b) {
  bf16x8 r;
  r[0] = (short)f2b(a.x); r[1] = (short)f2b(a.y);
  r[2] = (short)f2b(a.z); r[3] = (short)f2b(a.w);
  r[4] = (short)f2b(b.x); r[5] = (short)f2b(b.y);
  r[6] = (short)f2b(b.z); r[7] = (short)f2b(b.w);
  return r;
}

// ---------- graph preprocessing ----------
__global__ void k_histrank(const int* __restrict__ ei, int* __restrict__ cnt_p,
                           int* __restrict__ rank) {
  int e = blockIdx.x * blockDim.x + threadIdx.x;
  if (e >= NE) return;
  int dst = ei[NE + e];
  rank[e] = atomicAdd(&cnt_p[(size_t)dst * PAD], 1);
}

__global__ void k_scanA(const int* __restrict__ cnt_p, int* __restrict__ rs,
                        int* __restrict__ bsum) {
  __shared__ int sm[256];
  int j = threadIdx.x, i = blockIdx.x * 256 + j;
  int v = (i < NN) ? cnt_p[(size_t)i * PAD] : 0;
  sm[j] = v;
  __syncthreads();
  for (int off = 1; off < 256; off <<= 1) {
    int t = (j >= off) ? sm[j - off] : 0;
    __syncthreads();
    sm[j] += t;
    __syncthreads();
  }
  if (i < NN) rs[i] = sm[j] - v;
  if (j == 255) bsum[blockIdx.x] = sm[255];
}

__global__ void k_scanB(const int* __restrict__ bsum, int* __restrict__ boff) {
  __shared__ int sm[256];
  int j = threadIdx.x;
  const int nb = (NN + 255) / 256;
  int v = (j < nb) ? bsum[j] : 0;
  sm[j] = v;
  __syncthreads();
  for (int off = 1; off < 256; off <<= 1) {
    int t = (j >= off) ? sm[j - off] : 0;
    __syncthreads();
    sm[j] += t;
    __syncthreads();
  }
  if (j < nb) boff[j] = sm[j] - v;
}

__global__ void k_scanC(int* __restrict__ rs, const int* __restrict__ boff) {
  int i = blockIdx.x * blockDim.x + threadIdx.x;
  if (i < NN) rs[i] = rs[i] + boff[i >> 8];
  if (i == 0) rs[NN] = NE;
}

__global__ void k_place(const int* __restrict__ ei, const float* __restrict__ ew,
                        const float* __restrict__ ea, const int* __restrict__ rank,
                        const int* __restrict__ rs,
                        uint2* __restrict__ rec, float* __restrict__ scal) {
  int e = blockIdx.x * blockDim.x + threadIdx.x;
  float a = 0.f;
  if (e < NE) {
    int src = ei[e];
    int dst = ei[NE + e];
    float w = ew[e];
    a = ea[e];
    int slot = rs[dst] + rank[e];
    uint2 r;
    r.x = (uint_t)(src & 0xFFFF) | ((uint_t)f2h(w) << 16);
    r.y = (uint_t)(src & 0xFFFF) | ((uint_t)f2h(a) << 16);
    rec[slot] = r;
  }
  float s = wave_sum64(a);
  if ((threadIdx.x & 63) == 0) {
    int slot = (blockIdx.x * 4 + (threadIdx.x >> 6)) & 63;
    atomicAdd(&scal[(size_t)slot * 16], s);
  }
}

__global__ void k_deg(const uint_t* __restrict__ rec, const int* __restrict__ rs,
                      float* __restrict__ dinv, float* __restrict__ scal) {
  int i = blockIdx.x * blockDim.x + threadIdx.x;
  if (i < NN) {
    float s = 1.f;
    int k1 = rs[i + 1];
    for (int k = rs[i]; k < k1; ++k) s += h2f(rec[2 * k] >> 16);
    dinv[i] = rsqrtf(s);
  }
  if (i == 0) {
    float t = 0.f;
    for (int j = 0; j < 64; ++j) t += scal[(size_t)j * 16];
    scal[1] = t / (float)NE;
  }
}

// ---------- MFMA dense ops (unchanged) ----------
__global__ void __launch_bounds__(256) k_dual_gemm(
    const float* __restrict__ x, const float* __restrict__ W1,
    const float* __restrict__ W2, const float* __restrict__ b2,
    ushort_t* __restrict__ out1, float* __restrict__ out2) {
  __shared__ ushort_t wf[2 * 2 * 4 * 512];
  for (int e = threadIdx.x; e < 8192; e += 256) {
    int f = e >> 9, r = e & 511;
    int lane = r >> 3, j = r & 7;
    int m = f >> 3, s = (f >> 2) & 1, t = f & 3;
    int k = s * 32 + (lane >> 4) * 8 + j;
    int n = t * 16 + (lane & 15);
    const float* Wm = m ? W2 : W1;
    wf[e] = f2b(Wm[k * D + n]);
  }
  __syncthreads();
  int tile = blockIdx.x * 4 + (threadIdx.x >> 6);
  if (tile >= NT) return;
  int l = threadIdx.x & 63;
  int q = l >> 4, cn = l & 15;
  const float* xr = x + ((size_t)tile * 16 + cn) * D + q * 8;
  float4 xa = *(const float4*)xr;
  float4 xb = *(const float4*)(xr + 4);
  float4 xc = *(const float4*)(xr + 32);
  float4 xd = *(const float4*)(xr + 36);
  bf16x8 a0 = pack8(xa, xb), a1 = pack8(xc, xd);
  f32x4 acc1[4], acc2[4];
#pragma unroll
  for (int t = 0; t < 4; ++t) {
    bf16x8 b10 = *(const bf16x8*)&wf[(0 * 8 + 0 * 4 + t) * 512 + l * 8];
    bf16x8 b11 = *(const bf16x8*)&wf[(0 * 8 + 1 * 4 + t) * 512 + l * 8];
    bf16x8 b20 = *(const bf16x8*)&wf[(1 * 8 + 0 * 4 + t) * 512 + l * 8];
    bf16x8 b21 = *(const bf16x8*)&wf[(1 * 8 + 1 * 4 + t) * 512 + l * 8];
    f32x4 z = {0.f, 0.f, 0.f, 0.f};
    acc1[t] = __builtin_amdgcn_mfma_f32_16x16x32_bf16(a0, b10, z, 0, 0, 0);
    acc1[t] = __builtin_amdgcn_mfma_f32_16x16x32_bf16(a1, b11, acc1[t], 0, 0, 0);
    acc2[t] = __builtin_amdgcn_mfma_f32_16x16x32_bf16(a0, b20, z, 0, 0, 0);
    acc2[t] = __builtin_amdgcn_mfma_f32_16x16x32_bf16(a1, b21, acc2[t], 0, 0, 0);
  }
#pragma unroll
  for (int t = 0; t < 4; ++t) {
    float bb = b2[t * 16 + cn];
#pragma unroll
    for (int r = 0; r < 4; ++r) {
      size_t row = (size_t)tile * 16 + q * 4 + r;
      out1[row * D + t * 16 + cn] = f2b(acc1[t][r]);
      out2[row * D + t * 16 + cn] = acc2[t][r] + bb;
    }
  }
}

__global__ void __launch_bounds__(256) k_gat_node(
    const float* __restrict__ x2, const float* __restrict__ Wg,
    const float* __restrict__ att_src, const float* __restrict__ att_dst,
    const float* __restrict__ We, const float* __restrict__ a_e,
    ushort_t* __restrict__ xl, float* __restrict__ a_s, float* __restrict__ a_d,
    float* __restrict__ wea) {
  __shared__ ushort_t wf[2 * 4 * 512];
  for (int e = threadIdx.x; e < 4096; e += 256) {
    int f = e >> 9, r = e & 511;
    int lane = r >> 3, j = r & 7;
    int s = (f >> 2) & 1, t = f & 3;
    int k = s * 32 + (lane >> 4) * 8 + j;
    int n = t * 16 + (lane & 15);
    wf[e] = f2b(Wg[k * D + n]);
  }
  __syncthreads();
  if (blockIdx.x == 0 && threadIdx.x < 64) {
    int c = threadIdx.x;
    float v = group_sum16(We[c] * a_e[c]);
    if ((c & 15) == 0) wea[c >> 4] = v;
  }
  int tile = blockIdx.x * 4 + (threadIdx.x >> 6);
  if (tile >= NT) return;
  int l = threadIdx.x & 63;
  int q = l >> 4, cn = l & 15;
  const float* xr = x2 + ((size_t)tile * 16 + cn) * D + q * 8;
  float4 xa = *(const float4*)xr;
  float4 xb = *(const float4*)(xr + 4);
  float4 xc = *(const float4*)(xr + 32);
  float4 xd = *(const float4*)(xr + 36);
  bf16x8 a0 = pack8(xa, xb), a1 = pack8(xc, xd);
  f32x4 acc[4];
#pragma unroll
  for (int t = 0; t < 4; ++t) {
    bf16x8 b0 = *(const bf16x8*)&wf[(0 * 4 + t) * 512 + l * 8];
    bf16x8 b1 = *(const bf16x8*)&wf[(1 * 4 + t) * 512 + l * 8];
    f32x4 z = {0.f, 0.f, 0.f, 0.f};
    acc[t] = __builtin_amdgcn_mfma_f32_16x16x32_bf16(a0, b0, z, 0, 0, 0);
    acc[t] = __builtin_amdgcn_mfma_f32_16x16x32_bf16(a1, b1, acc[t], 0, 0, 0);
  }
#pragma unroll
  for (int t = 0; t < 4; ++t) {
    float av = att_src[t * 16 + cn];
    float dv = att_dst[t * 16 + cn];
#pragma unroll
    for (int r = 0; r < 4; ++r) {
      size_t row = (size_t)tile * 16 + q * 4 + r;
      xl[row * D + t * 16 + cn] = f2b(acc[t][r]);
      float vs = group_sum16(acc[t][r] * av);
      float vd = group_sum16(acc[t][r] * dv);
      if (cn == 0) {
        a_s[row * 4 + t] = vs;
        a_d[row * 4 + t] = vd;
      }
    }
  }
}

// ---------- aggregation: TWO nodes per wave (A,B) -> 2x independent gather
// chains per wave. Stage: lanes 0-31 stage A's edges (32-slot chunks),
// lanes 32-63 stage B's. Inner loop interleaves A/B row gathers. ----------

__global__ void __launch_bounds__(256) k_gcn_agg(
    const ushort_t* __restrict__ h16, const float* __restrict__ res,
    const float* __restrict__ dinv, const int* __restrict__ rs,
    const uint_t* __restrict__ rec,
    const float* __restrict__ gb, const float* __restrict__ lg, const float* __restrict__ lb,
    float* __restrict__ x2, int n) {
  __shared__ int   ss[4][64];
  __shared__ float swt[4][64];
  int w = threadIdx.x >> 6;
  int wv = (blockIdx.x * blockDim.x + threadIdx.x) >> 6;
  int iA = wv * 2;
  if (iA >= n) return;
  int iB = iA + 1;  // n even -> always valid
  int l = threadIdx.x & 63;
  int half = l >> 5, cp = l & 31;
  float diA = dinv[iA], diB = dinv[iB];
  float accA = diA * diA * b2f(h16[(size_t)iA * D + l]);
  float accB = diB * diB * b2f(h16[(size_t)iB * D + l]);
  int kA = rs[iA], kA1 = rs[iA + 1];
  int kB = rs[iB], kB1 = rs[iB + 1];
  while (kA < kA1 || kB < kB1) {
    int cntA = min(32, kA1 - kA);
    int cntB = min(32, kB1 - kB);
    int src = 0; float wn = 0.f;
    if (half == 0) {
      if (cp < cntA) {
        uint_t r = rec[2 * (size_t)(kA + cp)];
        src = (int)(r & 0xFFFFu);
        wn = dinv[src] * h2f(r >> 16) * diA;
      }
    } else {
      if (cp < cntB) {
        uint_t r = rec[2 * (size_t)(kB + cp)];
        src = (int)(r & 0xFFFFu);
        wn = dinv[src] * h2f(r >> 16) * diB;
      }
    }
    ss[w][l] = src;
    swt[w][l] = wn;
    int nm = max(cntA, cntB);
    int j = 0;
    for (; j + 4 <= nm; j += 4) {
      int4 sa = *(const int4*)&ss[w][j];
      int4 sb = *(const int4*)&ss[w][32 + j];
      float4 wa = *(const float4*)&swt[w][j];
      float4 wb = *(const float4*)&swt[w][32 + j];
      float a0 = b2f(h16[(size_t)sa.x * D + l]);
      float b0 = b2f(h16[(size_t)sb.x * D + l]);
      float a1 = b2f(h16[(size_t)sa.y * D + l]);
      float b1 = b2f(h16[(size_t)sb.y * D + l]);
      float a2 = b2f(h16[(size_t)sa.z * D + l]);
      float b2v = b2f(h16[(size_t)sb.z * D + l]);
      float a3 = b2f(h16[(size_t)sa.w * D + l]);
      float b3 = b2f(h16[(size_t)sb.w * D + l]);
      accA = fmaf(wa.x, a0, accA); accB = fmaf(wb.x, b0, accB);
      accA = fmaf(wa.y, a1, accA); accB = fmaf(wb.y, b1, accB);
      accA = fmaf(wa.z, a2, accA); accB = fmaf(wb.z, b2v, accB);
      accA = fmaf(wa.w, a3, accA); accB = fmaf(wb.w, b3, accB);
    }
    for (; j < nm; ++j) {
      int sA = ss[w][j], sB = ss[w][32 + j];
      float wA = swt[w][j], wB = swt[w][32 + j];
      float vA = b2f(h16[(size_t)sA * D + l]);
      float vB = b2f(h16[(size_t)sB * D + l]);
      accA = fmaf(wA, vA, accA);
      accB = fmaf(wB, vB, accB);
    }
    kA += cntA; kB += cntB;
  }
  float gbv = gb[l], lgv = lg[l], lbv = lb[l];
  float x1A = silu_f(accA + gbv) + res[(size_t)iA * D + l];
  float x1B = silu_f(accB + gbv) + res[(size_t)iB * D + l];
  float muA = wave_sum64(x1A) * (1.f / 64.f);
  float muB = wave_sum64(x1B) * (1.f / 64.f);
  float dA = x1A - muA, dB = x1B - muB;
  float varA = wave_sum64(dA * dA) * (1.f / 64.f);
  float varB = wave_sum64(dB * dB) * (1.f / 64.f);
  x2[(size_t)iA * D + l] = dA * rsqrtf(varA + EPS) * lgv + lbv;
  x2[(size_t)iB * D + l] = dB * rsqrtf(varB + EPS) * lgv + lbv;
}

__global__ void __launch_bounds__(256) k_gat_agg(
    const ushort_t* __restrict__ xl16, const float* __restrict__ x2,
    const float* __restrict__ a_s, const float* __restrict__ a_d,
    const int* __restrict__ rs, const uint_t* __restrict__ rec,
    const float* __restrict__ wea, const float* __restrict__ scal,
    const float* __restrict__ bg, float* __restrict__ xout, int n) {
  __shared__ int   ss[4][64];
  __shared__ float el[4][4][68];
  int w = threadIdx.x >> 6;
  int wv = (blockIdx.x * blockDim.x + threadIdx.x) >> 6;
  int iA = wv * 2;
  if (iA >= n) return;
  int iB = iA + 1;
  int l = threadIdx.x & 63;
  int half = l >> 5, cp = l & 31;
  int hh = l >> 4;
  float4 wv4 = *(const float4*)wea;
  float mean_attr = scal[1];
  float we_h = sel4(wv4.x, wv4.y, wv4.z, wv4.w, hh);
  float ad_hA = a_d[(size_t)iA * 4 + hh], as_iA = a_s[(size_t)iA * 4 + hh];
  float ad_hB = a_d[(size_t)iB * 4 + hh], as_iB = a_s[(size_t)iB * 4 + hh];
  float eSA = __expf(lrelu_f(as_iA + ad_hA + mean_attr * we_h));
  float eSB = __expf(lrelu_f(as_iB + ad_hB + mean_attr * we_h));
  float sA = eSA, sB = eSB;
  float accA = eSA * b2f(xl16[(size_t)iA * D + l]);
  float accB = eSB * b2f(xl16[(size_t)iB * D + l]);
  // per-half dst-node attention vector for staging
  const float* adp = a_d + (size_t)(half ? iB : iA) * 4;
  float4 ad4 = *(const float4*)adp;
  int kA = rs[iA], kA1 = rs[iA + 1];
  int kB = rs[iB], kB1 = rs[iB + 1];
  while (kA < kA1 || kB < kB1) {
    int cntA = min(32, kA1 - kA);
    int cntB = min(32, kB1 - kB);
    int myk = half ? kB : kA;
    int mycnt = half ? cntB : cntA;
    int src = 0;
    float e0v = 0.f, e1v = 0.f, e2v = 0.f, e3v = 0.f;
    if (cp < mycnt) {
      uint_t r = rec[2 * (size_t)(myk + cp) + 1];
      src = (int)(r & 0xFFFFu);
      float ea = h2f(r >> 16);
      float4 as4 = *(const float4*)(a_s + (size_t)src * 4);
      e0v = __expf(lrelu_f(as4.x + fmaf(ea, wv4.x, ad4.x)));
      e1v = __expf(lrelu_f(as4.y + fmaf(ea, wv4.y, ad4.y)));
      e2v = __expf(lrelu_f(as4.z + fmaf(ea, wv4.z, ad4.z)));
      e3v = __expf(lrelu_f(as4.w + fmaf(ea, wv4.w, ad4.w)));
    }
    ss[w][l] = src;
    el[w][0][l] = e0v;
    el[w][1][l] = e1v;
    el[w][2][l] = e2v;
    el[w][3][l] = e3v;
    int nm = max(cntA, cntB);
    int j = 0;
    for (; j + 4 <= nm; j += 4) {
      int4 sa = *(const int4*)&ss[w][j];
      int4 sb = *(const int4*)&ss[w][32 + j];
      float4 ea4 = *(const float4*)&el[w][hh][j];
      float4 eb4 = *(const float4*)&el[w][hh][32 + j];
      float a0 = b2f(xl16[(size_t)sa.x * D + l]);
      float b0 = b2f(xl16[(size_t)sb.x * D + l]);
      float a1 = b2f(xl16[(size_t)sa.y * D + l]);
      float b1 = b2f(xl16[(size_t)sb.y * D + l]);
      float a2 = b2f(xl16[(size_t)sa.z * D + l]);
      float b2v = b2f(xl16[(size_t)sb.z * D + l]);
      float a3 = b2f(xl16[(size_t)sa.w * D + l]);
      float b3 = b2f(xl16[(size_t)sb.w * D + l]);
      accA = fmaf(ea4.x, a0, accA); accB = fmaf(eb4.x, b0, accB);
      accA = fmaf(ea4.y, a1, accA); accB = fmaf(eb4.y, b1, accB);
      accA = fmaf(ea4.z, a2, accA); accB = fmaf(eb4.z, b2v, accB);
      accA = fmaf(ea4.w, a3, accA); accB = fmaf(eb4.w, b3, accB);
      sA += (ea4.x + ea4.y) + (ea4.z + ea4.w);
      sB += (eb4.x + eb4.y) + (eb4.z + eb4.w);
    }
    for (; j < nm; ++j) {
      int srcA = ss[w][j], srcB = ss[w][32 + j];
      float eA = el[w][hh][j], eB = el[w][hh][32 + j];
      float vA = b2f(xl16[(size_t)srcA * D + l]);
      float vB = b2f(xl16[(size_t)srcB * D + l]);
      accA = fmaf(eA, vA, accA);
      accB = fmaf(eB, vB, accB);
      sA += eA; sB += eB;
    }
    kA += cntA; kB += cntB;
  }
  float bgv = bg[l];
  float oA = accA / (sA + 1e-16f) + bgv;
  float oB = accB / (sB + 1e-16f) + bgv;
  xout[(size_t)iA * D + l] = silu_f(oA) + x2[(size_t)iA * D + l];
  xout[(size_t)iB * D + l] = silu_f(oB) + x2[(size_t)iB * D + l];
}

// ---------- launch ----------

extern "C" void kernel_launch(void* const* d_in, const int* in_sizes, int n_in,
                              void* d_out, int out_size, void* d_ws, size_t ws_size,
                              hipStream_t stream) {
  (void)in_sizes; (void)n_in; (void)out_size; (void)ws_size;
  const float* x  = (const float*)d_in[0];
  const int*   ei = (const int*)d_in[1];
  const float* ew = (const float*)d_in[2];
  const float* ea = (const float*)d_in[3];
  const float* P[2][12];
  for (int l = 0; l < 2; ++l)
    for (int j = 0; j < 12; ++j) P[l][j] = (const float*)d_in[4 + l * 12 + j];

  float* W = (float*)d_ws;
  const size_t o_rs    = 0;                          // NN+16 ints
  const size_t o_dinv  = o_rs + NN + 16;             // NN
  const size_t o_bsum  = o_dinv + NN;                // 256
  const size_t o_boff  = o_bsum + 256;               // 256
  const size_t o_wea   = o_boff + 256;               // 16
  const size_t o_scal  = o_wea + 16;                 // 1024 (contiguous w/ cnt_p)
  const size_t o_cnt   = o_scal + 1024;              // NN*PAD ints
  const size_t o_rec   = o_cnt + (size_t)NN * PAD;   // NE uint2
  const size_t o_h16   = o_rec + (size_t)NE * 2;     // NN*D ushort
  const size_t o_xl16  = o_h16 + (size_t)NN * D / 2;
  const size_t o_res   = o_xl16 + (size_t)NN * D / 2;
  const size_t o_x2    = o_res + (size_t)NN * D;
  const size_t o_xmid  = o_x2 + (size_t)NN * D;      // aliases rank in prep
  const size_t o_as    = o_xmid + (size_t)NN * D;    // NN*4
  const size_t o_ad    = o_as + (size_t)NN * 4;      // NN*4

  int*      rs    = (int*)(W + o_rs);
  float*    dinv  = W + o_dinv;
  int*      bsum  = (int*)(W + o_bsum);
  int*      boff  = (int*)(W + o_boff);
  float*    wea   = W + o_wea;
  float*    scal  = W + o_scal;
  int*      cnt_p = (int*)(W + o_cnt);
  uint2*    rec   = (uint2*)(W + o_rec);
  ushort_t* h16   = (ushort_t*)(W + o_h16);
  ushort_t* xl16  = (ushort_t*)(W + o_xl16);
  float*    resb  = W + o_res;
  float*    x2b   = W + o_x2;
  float*    xmid  = W + o_xmid;
  float*    asb   = W + o_as;
  float*    adb   = W + o_ad;
  int*      rank  = (int*)xmid;  // prep alias

  const int B = 256;
  const int gN  = (NN + B - 1) / B;
  const int gE  = (NE + B - 1) / B;
  const int gN2 = ((NN / 2) * 64 + B - 1) / B;  // 2 nodes per wave (agg kernels)
  const int gMF = (NT + 3) / 4;                 // 4 tiles (waves) per block

  hipMemsetAsync(W + o_scal, 0, (1024 + (size_t)NN * PAD) * sizeof(float), stream);
  k_histrank<<<gE, B, 0, stream>>>(ei, cnt_p, rank);
  k_scanA<<<gN, 256, 0, stream>>>(cnt_p, rs, bsum);
  k_scanB<<<1, 256, 0, stream>>>(bsum, boff);
  k_scanC<<<gN, B, 0, stream>>>(rs, boff);
  k_place<<<gE, B, 0, stream>>>(ei, ew, ea, rank, rs, rec, scal);
  k_deg<<<gN, B, 0, stream>>>((const uint_t*)rec, rs, dinv, scal);

  const float* xin = x;
  for (int l = 0; l < 2; ++l) {
    float* xout = (l == 0) ? xmid : (float*)d_out;
    k_dual_gemm<<<gMF, B, 0, stream>>>(xin, P[l][0], P[l][2], P[l][3], h16, resb);
    k_gcn_agg<<<gN2, B, 0, stream>>>(h16, resb, dinv, rs, (const uint_t*)rec,
                                     P[l][1], P[l][4], P[l][5], x2b, NN);
    k_gat_node<<<gMF, B, 0, stream>>>(x2b, P[l][6], P[l][8], P[l][9],
                                      P[l][11], P[l][10], xl16, asb, adb, wea);
    k_gat_agg<<<gN2, B, 0, stream>>>(xl16, x2b, asb, adb, rs, (const uint_t*)rec,
                                     wea, scal, P[l][7], xout, NN);
    xin = xout;
  }
}